// Round 25
// baseline (139.077 us; speedup 1.0000x reference)
//
#include <hip/hip_runtime.h>
#include <hip/hip_bf16.h>
#include <cstdint>

typedef __attribute__((ext_vector_type(8))) short short8;
typedef __attribute__((ext_vector_type(4))) float f32x4;
typedef __attribute__((ext_vector_type(16))) float f32x16;
typedef __attribute__((ext_vector_type(4))) unsigned uint4v;

#define DEV static __device__ __forceinline__

DEV f32x4 mfma16(short8 a, short8 b, f32x4 c) {
    return __builtin_amdgcn_mfma_f32_16x16x32_bf16(a, b, c, 0, 0, 0);
}
DEV f32x16 mfma32(short8 a, short8 b, f32x16 c) {
    return __builtin_amdgcn_mfma_f32_32x32x16_bf16(a, b, c, 0, 0, 0);
}

DEV unsigned short f2bf(float f) {
    __hip_bfloat16 h = __float2bfloat16(f);
    return __builtin_bit_cast(unsigned short, h);
}

// raw hardware exp2: 1 trans-pipe instruction (no libm range-check expansion).
DEV float fexp2(float x) {
#if __has_builtin(__builtin_amdgcn_exp2f)
    return __builtin_amdgcn_exp2f(x);
#else
    float r;
    asm("v_exp_f32 %0, %1" : "=v"(r) : "v"(x));
    return r;
#endif
}

// pack two f32 -> two bf16 in a u32 (lo = first arg), RNE
DEV unsigned cvtpk(float lo, float hi) {
    unsigned r;
    asm("v_cvt_pk_bf16_f32 %0, %1, %2" : "=v"(r) : "v"(lo), "v"(hi));
    return r;
}
// vdst_hi <-> vsrc_lo swap: after, a = {a_lo, b_lo}, b = {a_hi, b_hi}
DEV void plswap(unsigned& a, unsigned& b) {
    asm volatile("v_permlane32_swap_b32 %0, %1" : "+v"(a), "+v"(b));
}

// global -> LDS direct load, 16B per lane. Dest: wave-uniform base + lane*16.
#define GLOAD16(gp, lp)                                                        \
    __builtin_amdgcn_global_load_lds(                                          \
        (const __attribute__((address_space(1))) unsigned int*)(uintptr_t)(gp),\
        (__attribute__((address_space(3))) unsigned int*)(uintptr_t)(lp),      \
        16, 0, 0)

// ---------------- fused prep kernel (one launch, block-range dispatch) ----------------
// blocks [0, 8192):  f32->bf16 convert of x | qkv_w | fc_w
// blocks [8192, 8704): mask -> transposed bit-words wT[kb][row]
// block  8704:        sinusoidal pe table (256 threads cover 512 entries)
__global__ void prep(const float* __restrict__ x, const float* __restrict__ wq,
                     const float* __restrict__ wf, const int* __restrict__ mask,
                     unsigned short* __restrict__ xb, unsigned short* __restrict__ wqb,
                     unsigned short* __restrict__ wfb, unsigned int* __restrict__ wT,
                     float* __restrict__ pe) {
    const int bid = blockIdx.x;
    if (bid < 8192) {
        int i = bid * 256 + threadIdx.x;             // 0..2097151
        const float* src; unsigned short* dst; int off;
        if (i < 1048576)      { src = x;  dst = xb;  off = i; }
        else if (i < 1835008) { src = wq; dst = wqb; off = i - 1048576; }
        else                  { src = wf; dst = wfb; off = i - 1835008; }
        float4 v = ((const float4*)src)[off];
        ushort4 o;
        o.x = f2bf(v.x); o.y = f2bf(v.y); o.z = f2bf(v.z); o.w = f2bf(v.w);
        ((ushort4*)dst)[off] = o;
    } else if (bid < 8704) {
        int o = (bid - 8192) * 256 + threadIdx.x;    // 0..131071
        int kb = o >> 11, row = o & 2047;
        const int4* m4 = (const int4*)(mask + (size_t)row * 2048 + kb * 32);
        unsigned int bits = 0;
#pragma unroll
        for (int j = 0; j < 8; j++) {
            int4 v = m4[j];
            bits |= (unsigned)(v.x & 1) << (4 * j);
            bits |= (unsigned)(v.y & 1) << (4 * j + 1);
            bits |= (unsigned)(v.z & 1) << (4 * j + 2);
            bits |= (unsigned)(v.w & 1) << (4 * j + 3);
        }
        wT[o] = bits;
    } else {
        for (int i = threadIdx.x; i < 512; i += 256) {
            float div = expf((float)(2 * i) * (-9.210340371976184f / 1024.0f));
            pe[2 * i]          = 0.0f;      // sin(0*div)
            pe[2 * i + 1]      = 1.0f;      // cos(0*div)
            pe[1024 + 2 * i]     = sinf(div);
            pe[1024 + 2 * i + 1] = cosf(div);
        }
    }
}

// qkv GEMM: 64x128 tile (R25: R22-proven fc structure ported; 6 blocks/CU).
// Grid 1536 = 8 XCD x 192 (bijective swizzle). Epilogue +bias, +pe (q,k),
// q *= 1/8*log2e; FRAGMENT-MAJOR outputs staged in LDS as 4 complete 2048-short
// chunks (2 s-tiles x 2 heads), then 4 coalesced dwordx4 stores/thread.
__global__ __launch_bounds__(256) void qkv_gemm(
    const unsigned short* __restrict__ x, const unsigned short* __restrict__ wq,
    const float* __restrict__ bias, const float* __restrict__ pe,
    unsigned short* __restrict__ qo, unsigned short* __restrict__ ko,
    unsigned short* __restrict__ vt) {
    __shared__ unsigned short SB[12288];   // mainloop: As(2x2048)|Bs(2x4096); epi: 4x2048
    const int lin = blockIdx.x;
    const int swz = (lin & 7) * 192 + (lin >> 3);
    const int m0 = (swz / 24) * 64, n0 = (swz % 24) * 128;

    const int t = threadIdx.x;
    const int w = t >> 6;
    const int l = t & 63, lr = l & 15, lg = l >> 4;
    const int wr = w >> 1, wc = w & 1;
    const int srow = t >> 2;
    const int scg = ((t & 3) ^ ((t >> 3) & 3)) * 8;
    f32x4 acc[2][4];
#pragma unroll
    for (int i = 0; i < 2; i++)
#pragma unroll
        for (int j = 0; j < 4; j++) acc[i][j] = f32x4{0.f, 0.f, 0.f, 0.f};

    unsigned short* As = SB;
    unsigned short* Bs = SB + 4096;
    const unsigned short* Ap = x + (size_t)(m0 + srow) * 1024 + scg;
    const unsigned short* Bp = wq + (size_t)(n0 + srow) * 1024 + scg;
    unsigned short* dA = As + w * 512;
    unsigned short* dB = Bs + w * 512;

    const int slot = (lg ^ ((lr >> 1) & 3)) * 8;
    const unsigned short* Ar = As + (wr * 32 + lr) * 32 + slot;
    const unsigned short* Br = Bs + (wc * 64 + lr) * 32 + slot;

#define STAGE(buf, k0)                                                \
    {                                                                 \
        GLOAD16(Ap + (k0), dA + (buf) * 2048);                        \
        GLOAD16(Bp + (k0), dB + (buf) * 4096);                        \
        GLOAD16(Bp + 64 * 1024 + (k0), dB + (buf) * 4096 + 2048);     \
    }

    STAGE(0, 0);
#pragma unroll 2
    for (int k0 = 0; k0 < 1024; k0 += 32) {
        const int cur = (k0 >> 5) & 1;
        __syncthreads();
        if (k0 + 32 < 1024) STAGE(cur ^ 1, k0 + 32);
        short8 af[2], bfr[4];
#pragma unroll
        for (int i = 0; i < 2; i++)
            af[i] = *(const short8*)(Ar + cur * 2048 + i * 512);
#pragma unroll
        for (int j = 0; j < 4; j++)
            bfr[j] = *(const short8*)(Br + cur * 4096 + j * 512);
#pragma unroll
        for (int i = 0; i < 2; i++)
#pragma unroll
            for (int j = 0; j < 4; j++)
                acc[i][j] = mfma16(af[i], bfr[j], acc[i][j]);
    }
#undef STAGE

    const int part = n0 >> 10;                // uniform per block
    const int h0 = (n0 & 1023) >> 6;
    const int b  = m0 >> 11;

    __syncthreads();   // all waves done with SB (mainloop) before overwrite
#pragma unroll
    for (int i = 0; i < 2; i++) {
#pragma unroll
        for (int j = 0; j < 4; j++) {
            const int n = n0 + wc * 64 + j * 16 + lr;
            const int d = n & 1023, hd = d & 63;
            const int h_loc = (d >> 6) & 1;
            const float bia = bias[n];
            const float pv = (part < 2) ? pe[b * 1024 + d] : 0.f;
#pragma unroll
            for (int r = 0; r < 4; r++) {
                const int m = m0 + wr * 32 + i * 16 + lg * 4 + r;
                const int s = m & 2047, s5 = s & 31, t_loc = (s >> 5) & 1;
                float v = acc[i][j][r] + bia;
                int inner;
                if (part == 2) {
                    inner = (hd >> 5) * 1024 + ((s5 >> 4) & 1) * 512 +
                            (((s5 >> 3) & 1) * 32 + (hd & 31)) * 8 + (s5 & 7);
                } else {
                    v += pv;
                    if (part == 0) v *= 0.1803368801111204f;   // 1/8 * log2(e)
                    inner = (hd >> 4) * 512 + (((hd >> 3) & 1) * 32 + s5) * 8 + (hd & 7);
                }
                SB[(t_loc * 2 + h_loc) * 2048 + inner] = f2bf(v);
            }
        }
    }
    __syncthreads();

    // linear copy: chunk cidx = t>>6 (4 chunks x 64 thr); each thread 32 shorts.
    // t_g = per-batch s-tile ((m0 & 2047) >> 5) + (cidx >> 1); bh = b*16 + h0 + (cidx&1).
    unsigned short* dst0 = (part == 0) ? qo : (part == 1) ? ko : vt;
    const int cidx = t >> 6;
    const int t_g = ((m0 & 2047) >> 5) + (cidx >> 1);
    const int bh = b * 16 + h0 + (cidx & 1);
    unsigned short* gdst = dst0 + (size_t)bh * 131072 + t_g * 2048 + (t & 63) * 32;
    const unsigned short* lsrc = SB + cidx * 2048 + (t & 63) * 32;
#pragma unroll
    for (int u = 0; u < 4; u++)
        *(short8*)(gdst + u * 8) = *(const short8*)(lsrc + u * 8);
}

// fc GEMM: 64x128 tile (R22-proven), grid 512 = 8 XCD x 64. out f32 += fc_b.
__global__ __launch_bounds__(256) void fc_gemm(
    const unsigned short* __restrict__ a, const unsigned short* __restrict__ wf,
    const float* __restrict__ bias, float* __restrict__ out) {
    __shared__ unsigned short As[2 * 2048], Bs[2 * 4096];
    const int lin = blockIdx.x;
    const int swz = (lin & 7) * 64 + (lin >> 3);
    const int m0 = (swz >> 3) * 64, n0 = (swz & 7) * 128;

    const int t = threadIdx.x;
    const int w = t >> 6;
    const int l = t & 63, lr = l & 15, lg = l >> 4;
    const int wr = w >> 1, wc = w & 1;
    const int srow = t >> 2;
    const int scg = ((t & 3) ^ ((t >> 3) & 3)) * 8;
    f32x4 acc[2][4];
#pragma unroll
    for (int i = 0; i < 2; i++)
#pragma unroll
        for (int j = 0; j < 4; j++) acc[i][j] = f32x4{0.f, 0.f, 0.f, 0.f};

    const unsigned short* Ap = a + (size_t)(m0 + srow) * 1024 + scg;
    const unsigned short* Bp = wf + (size_t)(n0 + srow) * 1024 + scg;
    unsigned short* dA = As + w * 512;
    unsigned short* dB = Bs + w * 512;

    const int slot = (lg ^ ((lr >> 1) & 3)) * 8;
    const unsigned short* Ar = As + (wr * 32 + lr) * 32 + slot;
    const unsigned short* Br = Bs + (wc * 64 + lr) * 32 + slot;

#define STAGE(buf, k0)                                                \
    {                                                                 \
        GLOAD16(Ap + (k0), dA + (buf) * 2048);                        \
        GLOAD16(Bp + (k0), dB + (buf) * 4096);                        \
        GLOAD16(Bp + 64 * 1024 + (k0), dB + (buf) * 4096 + 2048);     \
    }

    STAGE(0, 0);
#pragma unroll 2
    for (int k0 = 0; k0 < 1024; k0 += 32) {
        const int cur = (k0 >> 5) & 1;
        __syncthreads();
        if (k0 + 32 < 1024) STAGE(cur ^ 1, k0 + 32);
        short8 af[2], bfr[4];
#pragma unroll
        for (int i = 0; i < 2; i++)
            af[i] = *(const short8*)(Ar + cur * 2048 + i * 512);
#pragma unroll
        for (int j = 0; j < 4; j++)
            bfr[j] = *(const short8*)(Br + cur * 4096 + j * 512);
#pragma unroll
        for (int i = 0; i < 2; i++)
#pragma unroll
            for (int j = 0; j < 4; j++)
                acc[i][j] = mfma16(af[i], bfr[j], acc[i][j]);
    }
#undef STAGE

#pragma unroll
    for (int i = 0; i < 2; i++) {
#pragma unroll
        for (int j = 0; j < 4; j++) {
            const int n = n0 + wc * 64 + j * 16 + lr;
            const float bia = bias[n];
#pragma unroll
            for (int r = 0; r < 4; r++) {
                const int m = m0 + wr * 32 + i * 16 + lg * 4 + r;
                out[(size_t)m * 1024 + n] = acc[i][j][r] + bia;
            }
        }
    }
}

// ---- split-K flash attention (R24-proven): SPLIT=4 in-block, 2-region add-in combine.
__global__ __launch_bounds__(256, 3) void attn(
    const unsigned short* __restrict__ q, const unsigned short* __restrict__ k,
    const unsigned short* __restrict__ vt, const unsigned int* __restrict__ mw,
    unsigned short* __restrict__ ao) {
    __shared__ float CL[2][2080];   // 2 regions: [64d x 32q | 32 l], 16640 B total
    const int t = threadIdx.x, w = t >> 6;          // w = chunk 0..3
    const int l = t & 63, c = l & 31, hi = l >> 5;
    const int bid = blockIdx.x;                     // 0..2047
    const int xcd = bid & 7, idx = bid >> 3;        // idx 0..255
    const int bh = xcd * 4 + (idx & 3);
    const int qb = idx >> 2;                        // 0..63
    const int b = bh >> 4, h = bh & 15;
    const int kb0 = w * 16;                         // 16 kb per wave

    // fragment-major bases; every load below is  ptr + lane*8 shorts (16B)
    const unsigned short* qfb = q + (size_t)bh * 131072 + qb * 2048 + l * 8;
    const unsigned short* kfb = k + (size_t)bh * 131072 + l * 8;
    const unsigned short* vfb = vt + (size_t)bh * 131072 + l * 8;

    short8 qf[4];
#pragma unroll
    for (int d = 0; d < 4; d++)
        qf[d] = *(const short8*)(qfb + d * 512);

    // opaque zero C operand (loop-invariant; blocks per-iter zero re-materialization)
    float z = 0.f;
    asm volatile("" : "+v"(z));
    f32x16 FZ;
#pragma unroll
    for (int i = 0; i < 16; i++) FZ[i] = z;

    f32x16 OT0, OT1;
#pragma unroll
    for (int i = 0; i < 16; i++) { OT0[i] = 0.f; OT1[i] = 0.f; }
    float lrow = 0.f;

#pragma unroll 4
    for (int kb = kb0; kb < kb0 + 16; kb++) {
        // loads at use (no reg prefetch): K frags, V frags, mask word
        const unsigned short* kp = kfb + kb * 2048;
        const unsigned short* vp = vfb + kb * 2048;
        short8 kf[4], vf[2][2];
#pragma unroll
        for (int d = 0; d < 4; d++) kf[d] = *(const short8*)(kp + d * 512);
#pragma unroll
        for (int kc = 0; kc < 2; kc++) {
            vf[0][kc] = *(const short8*)(vp + kc * 512);
            vf[1][kc] = *(const short8*)(vp + 1024 + kc * 512);
        }
        const unsigned int wd = mw[kb * 2048 + qb * 32 + c];

        // QK^T; C = opaque zero
        __builtin_amdgcn_s_setprio(1);
        f32x16 S = mfma32(kf[0], qf[0], FZ);
#pragma unroll
        for (int d = 1; d < 4; d++) S = mfma32(kf[d], qf[d], S);
        __builtin_amdgcn_s_setprio(0);

        // mask -> -1e9, then p = 2^s via raw v_exp_f32 (exp2(-1e9) = 0 exactly)
        const unsigned int wds = wd >> (4 * hi);
        float p[16];
#pragma unroll
        for (int g = 0; g < 4; g++)
#pragma unroll
            for (int u = 0; u < 4; u++)
                p[g * 4 + u] = (wds & (1u << (8 * g + u))) ? -1e9f : S[g * 4 + u];
#pragma unroll
        for (int i = 0; i < 16; i++) p[i] = fexp2(p[i]);

        // f32 row-sum (R11-proven): in-lane tree + shfl_xor(32)
        float rs = (((p[0] + p[1]) + (p[2] + p[3])) + ((p[4] + p[5]) + (p[6] + p[7]))) +
                   (((p[8] + p[9]) + (p[10] + p[11])) + ((p[12] + p[13]) + (p[14] + p[15])));
        rs += __shfl_xor(rs, 32);
        lrow += rs;

        // P -> bf16 A-frag: 8 cvt_pk + 4 permlane32_swap (T12)
        unsigned w8[8];
#pragma unroll
        for (int g = 0; g < 4; g++) {
            w8[2 * g]     = cvtpk(p[4 * g], p[4 * g + 1]);
            w8[2 * g + 1] = cvtpk(p[4 * g + 2], p[4 * g + 3]);
        }
        short8 pa[2];
#pragma unroll
        for (int kc = 0; kc < 2; kc++) {
            unsigned a0 = w8[4 * kc], a2 = w8[4 * kc + 2];
            plswap(a0, a2);
            unsigned a1 = w8[4 * kc + 1], a3 = w8[4 * kc + 3];
            plswap(a1, a3);
            uint4v tv; tv[0] = a0; tv[1] = a1; tv[2] = a2; tv[3] = a3;
            pa[kc] = __builtin_bit_cast(short8, tv);
        }

        // PV: O^T[d][q] += V^T * P
        __builtin_amdgcn_s_setprio(1);
        OT0 = mfma32(vf[0][0], pa[0], OT0);
        OT0 = mfma32(vf[0][1], pa[1], OT0);
        OT1 = mfma32(vf[1][0], pa[0], OT1);
        OT1 = mfma32(vf[1][1], pa[1], OT1);
        __builtin_amdgcn_s_setprio(0);
    }

    // 2-region add-in combine. region r holds chunks {r, r+2} summed.
    float* R = CL[w & 1];
    if (w < 2) {
#pragma unroll
        for (int i = 0; i < 16; i++) {
            const int kr = (i & 3) + 8 * (i >> 2) + 4 * hi;
            R[kr * 32 + c]        = OT0[i];
            R[(32 + kr) * 32 + c] = OT1[i];
        }
        if (hi == 0) R[2048 + c] = lrow;
    }
    __syncthreads();
    if (w >= 2) {
#pragma unroll
        for (int i = 0; i < 16; i++) {
            const int kr = (i & 3) + 8 * (i >> 2) + 4 * hi;
            R[kr * 32 + c]        += OT0[i];
            R[(32 + kr) * 32 + c] += OT1[i];
        }
        if (hi == 0) R[2048 + c] += lrow;
    }
    __syncthreads();

    // final transpose-store: lane qq = l>>1; wave w covers d-quarter w*16, l&1 picks
    // the 8-col half. O = (region0 + region1) / (l0 + l1), 16B store per lane.
    const int qq = l >> 1, d0 = w * 16 + (l & 1) * 8;
    const float inv = 1.0f / (CL[0][2048 + qq] + CL[1][2048 + qq]);
    const int row = b * 2048 + qb * 32 + qq;
    unsigned short* gout = ao + (size_t)row * 1024 + h * 64 + d0;
    uint4v pk;
#pragma unroll
    for (int u = 0; u < 4; u++) {
        const int d = d0 + 2 * u;
        float a0 = CL[0][d * 32 + qq]       + CL[1][d * 32 + qq];
        float a1 = CL[0][(d + 1) * 32 + qq] + CL[1][(d + 1) * 32 + qq];
        pk[u] = cvtpk(a0 * inv, a1 * inv);
    }
    *(uint4v*)gout = pk;
}

// ---------------- launcher ----------------
extern "C" void kernel_launch(void* const* d_in, const int* in_sizes, int n_in,
                              void* d_out, int out_size, void* d_ws, size_t ws_size,
                              hipStream_t stream) {
    const float* x     = (const float*)d_in[0];
    const int*   mask  = (const int*)d_in[1];
    const float* qkv_w = (const float*)d_in[2];
    const float* qkv_b = (const float*)d_in[3];
    const float* fc_w  = (const float*)d_in[4];
    const float* fc_b  = (const float*)d_in[5];
    float* out = (float*)d_out;

    char* ws = (char*)d_ws;
    size_t off = 0;
    auto alloc = [&](size_t bytes) {
        off = (off + 255) & ~(size_t)255;
        void* p = ws + off;
        off += bytes;
        return p;
    };
    float*          pe     = (float*)alloc(2 * 1024 * 4);
    unsigned int*   mwords = (unsigned int*)alloc((size_t)2048 * 64 * 4);
    unsigned short* xb     = (unsigned short*)alloc((size_t)4096 * 1024 * 2);
    unsigned short* wqkv   = (unsigned short*)alloc((size_t)3072 * 1024 * 2);
    unsigned short* wfc    = (unsigned short*)alloc((size_t)1024 * 1024 * 2);
    unsigned short* qb16   = (unsigned short*)alloc((size_t)2 * 16 * 2048 * 64 * 2);
    unsigned short* kb16   = (unsigned short*)alloc((size_t)2 * 16 * 2048 * 64 * 2);
    unsigned short* vtb    = (unsigned short*)alloc((size_t)2 * 16 * 64 * 2048 * 2);
    unsigned short* attn_o = (unsigned short*)alloc((size_t)4096 * 1024 * 2);

    prep<<<dim3(8705), 256, 0, stream>>>(x, qkv_w, fc_w, mask, xb, wqkv, wfc, mwords, pe);
    qkv_gemm<<<dim3(1536), 256, 0, stream>>>(xb, wqkv, qkv_b, pe, qb16, kb16, vtb);
    attn<<<dim3(2048), 256, 0, stream>>>(qb16, kb16, vtb, mwords, attn_o);
    fc_gemm<<<dim3(512), 256, 0, stream>>>(attn_o, wfc, fc_b, out);
}

// Round 26
// 136.129 us; speedup vs baseline: 1.0217x; 1.0217x over previous
//
#include <hip/hip_runtime.h>
#include <hip/hip_bf16.h>
#include <cstdint>

typedef __attribute__((ext_vector_type(8))) short short8;
typedef __attribute__((ext_vector_type(4))) float f32x4;
typedef __attribute__((ext_vector_type(16))) float f32x16;
typedef __attribute__((ext_vector_type(4))) unsigned uint4v;

#define DEV static __device__ __forceinline__

DEV f32x4 mfma16(short8 a, short8 b, f32x4 c) {
    return __builtin_amdgcn_mfma_f32_16x16x32_bf16(a, b, c, 0, 0, 0);
}
DEV f32x16 mfma32(short8 a, short8 b, f32x16 c) {
    return __builtin_amdgcn_mfma_f32_32x32x16_bf16(a, b, c, 0, 0, 0);
}

DEV unsigned short f2bf(float f) {
    __hip_bfloat16 h = __float2bfloat16(f);
    return __builtin_bit_cast(unsigned short, h);
}

// raw hardware exp2: 1 trans-pipe instruction (no libm range-check expansion).
DEV float fexp2(float x) {
#if __has_builtin(__builtin_amdgcn_exp2f)
    return __builtin_amdgcn_exp2f(x);
#else
    float r;
    asm("v_exp_f32 %0, %1" : "=v"(r) : "v"(x));
    return r;
#endif
}

// pack two f32 -> two bf16 in a u32 (lo = first arg), RNE
DEV unsigned cvtpk(float lo, float hi) {
    unsigned r;
    asm("v_cvt_pk_bf16_f32 %0, %1, %2" : "=v"(r) : "v"(lo), "v"(hi));
    return r;
}
// vdst_hi <-> vsrc_lo swap: after, a = {a_lo, b_lo}, b = {a_hi, b_hi}
DEV void plswap(unsigned& a, unsigned& b) {
    asm volatile("v_permlane32_swap_b32 %0, %1" : "+v"(a), "+v"(b));
}

// global -> LDS direct load, 16B per lane. Dest: wave-uniform base + lane*16.
#define GLOAD16(gp, lp)                                                        \
    __builtin_amdgcn_global_load_lds(                                          \
        (const __attribute__((address_space(1))) unsigned int*)(uintptr_t)(gp),\
        (__attribute__((address_space(3))) unsigned int*)(uintptr_t)(lp),      \
        16, 0, 0)

// ---------------- fused prep kernel (one launch, block-range dispatch) ----------------
// blocks [0, 8192):  f32->bf16 convert of x | qkv_w | fc_w
// blocks [8192, 8704): mask -> transposed bit-words wT[kb][row]
// block  8704:        sinusoidal pe table (256 threads cover 512 entries)
__global__ void prep(const float* __restrict__ x, const float* __restrict__ wq,
                     const float* __restrict__ wf, const int* __restrict__ mask,
                     unsigned short* __restrict__ xb, unsigned short* __restrict__ wqb,
                     unsigned short* __restrict__ wfb, unsigned int* __restrict__ wT,
                     float* __restrict__ pe) {
    const int bid = blockIdx.x;
    if (bid < 8192) {
        int i = bid * 256 + threadIdx.x;             // 0..2097151
        const float* src; unsigned short* dst; int off;
        if (i < 1048576)      { src = x;  dst = xb;  off = i; }
        else if (i < 1835008) { src = wq; dst = wqb; off = i - 1048576; }
        else                  { src = wf; dst = wfb; off = i - 1835008; }
        float4 v = ((const float4*)src)[off];
        ushort4 o;
        o.x = f2bf(v.x); o.y = f2bf(v.y); o.z = f2bf(v.z); o.w = f2bf(v.w);
        ((ushort4*)dst)[off] = o;
    } else if (bid < 8704) {
        int o = (bid - 8192) * 256 + threadIdx.x;    // 0..131071
        int kb = o >> 11, row = o & 2047;
        const int4* m4 = (const int4*)(mask + (size_t)row * 2048 + kb * 32);
        unsigned int bits = 0;
#pragma unroll
        for (int j = 0; j < 8; j++) {
            int4 v = m4[j];
            bits |= (unsigned)(v.x & 1) << (4 * j);
            bits |= (unsigned)(v.y & 1) << (4 * j + 1);
            bits |= (unsigned)(v.z & 1) << (4 * j + 2);
            bits |= (unsigned)(v.w & 1) << (4 * j + 3);
        }
        wT[o] = bits;
    } else {
        for (int i = threadIdx.x; i < 512; i += 256) {
            float div = expf((float)(2 * i) * (-9.210340371976184f / 1024.0f));
            pe[2 * i]          = 0.0f;      // sin(0*div)
            pe[2 * i + 1]      = 1.0f;      // cos(0*div)
            pe[1024 + 2 * i]     = sinf(div);
            pe[1024 + 2 * i + 1] = cosf(div);
        }
    }
}

// ------- GEMM mainloop: 128x128 tile, BK=32, double-buffered LDS, swizzled reads -------
// (R15-proven.) Pre-swizzled SOURCE chunk + linear LDS dest; reads XOR the chunk slot.
DEV void gemm_mainloop(const unsigned short* __restrict__ A,
                       const unsigned short* __restrict__ Bm,
                       int m0, int n0, f32x4 (&acc)[4][4],
                       unsigned short* As, unsigned short* Bs) {   // each [2*4096]
    const int t = threadIdx.x;
    const int w = t >> 6;
    const int l = t & 63, lr = l & 15, lg = l >> 4;
    const int wr = w >> 1, wc = w & 1;
    const int srow = t >> 2;
    const int scg = ((t & 3) ^ ((t >> 3) & 3)) * 8;   // pre-swizzled source chunk
#pragma unroll
    for (int i = 0; i < 4; i++)
#pragma unroll
        for (int j = 0; j < 4; j++) acc[i][j] = f32x4{0.f, 0.f, 0.f, 0.f};

    const unsigned short* Ap = A + (size_t)(m0 + srow) * 1024 + scg;
    const unsigned short* Bp = Bm + (size_t)(n0 + srow) * 1024 + scg;
    unsigned short* dA = As + w * 512;
    unsigned short* dB = Bs + w * 512;

    // swizzled read bases (loop-invariant): slot = lg ^ ((lr>>1)&3)
    const int slot = (lg ^ ((lr >> 1) & 3)) * 8;
    const unsigned short* Ar = As + (wr * 64 + lr) * 32 + slot;
    const unsigned short* Br = Bs + (wc * 64 + lr) * 32 + slot;

#define STAGE(buf, k0)                                                \
    {                                                                 \
        GLOAD16(Ap + (k0), dA + (buf) * 4096);                        \
        GLOAD16(Ap + 64 * 1024 + (k0), dA + (buf) * 4096 + 2048);     \
        GLOAD16(Bp + (k0), dB + (buf) * 4096);                        \
        GLOAD16(Bp + 64 * 1024 + (k0), dB + (buf) * 4096 + 2048);     \
    }

    STAGE(0, 0);
#pragma unroll 2
    for (int k0 = 0; k0 < 1024; k0 += 32) {
        const int cur = (k0 >> 5) & 1;
        __syncthreads();                      // drains vmcnt: buf[cur] ready; prev reads done
        if (k0 + 32 < 1024) STAGE(cur ^ 1, k0 + 32);
        short8 af[4], bfr[4];
#pragma unroll
        for (int i = 0; i < 4; i++)
            af[i] = *(const short8*)(Ar + cur * 4096 + i * 512);
#pragma unroll
        for (int j = 0; j < 4; j++)
            bfr[j] = *(const short8*)(Br + cur * 4096 + j * 512);
#pragma unroll
        for (int i = 0; i < 4; i++)
#pragma unroll
            for (int j = 0; j < 4; j++)
                acc[i][j] = mfma16(af[i], bfr[j], acc[i][j]);
    }
#undef STAGE
}

// qkv GEMM: 1D grid 768 with XCD-aware swizzle (T1; 768 = 8*96, bijective).
// Epilogue +bias, +pe (q,k), q *= 1/8*log2e; FRAGMENT-MAJOR outputs via LDS.
__global__ __launch_bounds__(256) void qkv_gemm(
    const unsigned short* __restrict__ x, const unsigned short* __restrict__ wq,
    const float* __restrict__ bias, const float* __restrict__ pe,
    unsigned short* __restrict__ qo, unsigned short* __restrict__ ko,
    unsigned short* __restrict__ vt) {
    __shared__ unsigned short SB[16384];      // mainloop: As|Bs ; epilogue: 8x2048 chunks
    const int lin = blockIdx.x;
    const int swz = (lin & 7) * 96 + (lin >> 3);
    const int m0 = (swz / 24) * 128, n0 = (swz % 24) * 128;
    f32x4 acc[4][4];
    gemm_mainloop(x, wq, m0, n0, acc, SB, SB + 8192);

    const int t = threadIdx.x, w = t >> 6, l = t & 63;
    const int wr = w >> 1, wc = w & 1, lr = l & 15, lg = l >> 4;
    const int part = n0 >> 10;                // uniform per block (1024 % 128 == 0)
    const int h0 = (n0 & 1023) >> 6;
    const int b  = m0 >> 11;

    __syncthreads();   // all waves done with SB (mainloop) before overwrite
#pragma unroll
    for (int i = 0; i < 4; i++) {
#pragma unroll
        for (int j = 0; j < 4; j++) {
            const int n = n0 + wc * 64 + j * 16 + lr;
            const int d = n & 1023, hd = d & 63;
            const int h_loc = (d >> 6) & 1;
            const float bia = bias[n];
            const float pv = (part < 2) ? pe[b * 1024 + d] : 0.f;
#pragma unroll
            for (int r = 0; r < 4; r++) {
                const int m = m0 + wr * 64 + i * 16 + lg * 4 + r;
                const int s = m & 2047, s5 = s & 31, t_loc = (s >> 5) & 3;
                float v = acc[i][j][r] + bia;
                int inner;
                if (part == 2) {
                    inner = (hd >> 5) * 1024 + ((s5 >> 4) & 1) * 512 +
                            (((s5 >> 3) & 1) * 32 + (hd & 31)) * 8 + (s5 & 7);
                } else {
                    v += pv;
                    if (part == 0) v *= 0.1803368801111204f;   // 1/8 * log2(e)
                    inner = (hd >> 4) * 512 + (((hd >> 3) & 1) * 32 + s5) * 8 + (hd & 7);
                }
                SB[(t_loc * 2 + h_loc) * 2048 + inner] = f2bf(v);
            }
        }
    }
    __syncthreads();

    // linear copy: chunk cidx = t>>5 -> global fragment tile; t_g is PER-BATCH s-tile.
    unsigned short* dst0 = (part == 0) ? qo : (part == 1) ? ko : vt;
    const int cidx = t >> 5;
    const int t_g = ((m0 & 2047) >> 5) + (cidx >> 1);
    const int bh = b * 16 + h0 + (cidx & 1);
    unsigned short* gdst = dst0 + (size_t)bh * 131072 + t_g * 2048 + (t & 31) * 64;
    const unsigned short* lsrc = SB + cidx * 2048 + (t & 31) * 64;
#pragma unroll
    for (int u = 0; u < 8; u++)
        *(short8*)(gdst + u * 8) = *(const short8*)(lsrc + u * 8);
}

// fc GEMM: 64x128 tile (R22-proven), grid 512 = 8 XCD x 64. out f32 += fc_b.
__global__ __launch_bounds__(256) void fc_gemm(
    const unsigned short* __restrict__ a, const unsigned short* __restrict__ wf,
    const float* __restrict__ bias, float* __restrict__ out) {
    __shared__ unsigned short As[2 * 2048], Bs[2 * 4096];
    const int lin = blockIdx.x;
    const int swz = (lin & 7) * 64 + (lin >> 3);
    const int m0 = (swz >> 3) * 64, n0 = (swz & 7) * 128;

    const int t = threadIdx.x;
    const int w = t >> 6;
    const int l = t & 63, lr = l & 15, lg = l >> 4;
    const int wr = w >> 1, wc = w & 1;
    const int srow = t >> 2;
    const int scg = ((t & 3) ^ ((t >> 3) & 3)) * 8;
    f32x4 acc[2][4];
#pragma unroll
    for (int i = 0; i < 2; i++)
#pragma unroll
        for (int j = 0; j < 4; j++) acc[i][j] = f32x4{0.f, 0.f, 0.f, 0.f};

    const unsigned short* Ap = a + (size_t)(m0 + srow) * 1024 + scg;
    const unsigned short* Bp = wf + (size_t)(n0 + srow) * 1024 + scg;
    unsigned short* dA = As + w * 512;
    unsigned short* dB = Bs + w * 512;

    const int slot = (lg ^ ((lr >> 1) & 3)) * 8;
    const unsigned short* Ar = As + (wr * 32 + lr) * 32 + slot;
    const unsigned short* Br = Bs + (wc * 64 + lr) * 32 + slot;

#define STAGE(buf, k0)                                                \
    {                                                                 \
        GLOAD16(Ap + (k0), dA + (buf) * 2048);                        \
        GLOAD16(Bp + (k0), dB + (buf) * 4096);                        \
        GLOAD16(Bp + 64 * 1024 + (k0), dB + (buf) * 4096 + 2048);     \
    }

    STAGE(0, 0);
#pragma unroll 2
    for (int k0 = 0; k0 < 1024; k0 += 32) {
        const int cur = (k0 >> 5) & 1;
        __syncthreads();
        if (k0 + 32 < 1024) STAGE(cur ^ 1, k0 + 32);
        short8 af[2], bfr[4];
#pragma unroll
        for (int i = 0; i < 2; i++)
            af[i] = *(const short8*)(Ar + cur * 2048 + i * 512);
#pragma unroll
        for (int j = 0; j < 4; j++)
            bfr[j] = *(const short8*)(Br + cur * 4096 + j * 512);
#pragma unroll
        for (int i = 0; i < 2; i++)
#pragma unroll
            for (int j = 0; j < 4; j++)
                acc[i][j] = mfma16(af[i], bfr[j], acc[i][j]);
    }
#undef STAGE

#pragma unroll
    for (int i = 0; i < 2; i++) {
#pragma unroll
        for (int j = 0; j < 4; j++) {
            const int n = n0 + wc * 64 + j * 16 + lr;
            const float bia = bias[n];
#pragma unroll
            for (int r = 0; r < 4; r++) {
                const int m = m0 + wr * 32 + i * 16 + lg * 4 + r;
                out[(size_t)m * 1024 + n] = acc[i][j][r] + bia;
            }
        }
    }
}

// ---- split-K flash attention (R24-proven): SPLIT=4 in-block, 2-region add-in combine.
__global__ __launch_bounds__(256, 3) void attn(
    const unsigned short* __restrict__ q, const unsigned short* __restrict__ k,
    const unsigned short* __restrict__ vt, const unsigned int* __restrict__ mw,
    unsigned short* __restrict__ ao) {
    __shared__ float CL[2][2080];   // 2 regions: [64d x 32q | 32 l], 16640 B total
    const int t = threadIdx.x, w = t >> 6;          // w = chunk 0..3
    const int l = t & 63, c = l & 31, hi = l >> 5;
    const int bid = blockIdx.x;                     // 0..2047
    const int xcd = bid & 7, idx = bid >> 3;        // idx 0..255
    const int bh = xcd * 4 + (idx & 3);
    const int qb = idx >> 2;                        // 0..63
    const int b = bh >> 4, h = bh & 15;
    const int kb0 = w * 16;                         // 16 kb per wave

    // fragment-major bases; every load below is  ptr + lane*8 shorts (16B)
    const unsigned short* qfb = q + (size_t)bh * 131072 + qb * 2048 + l * 8;
    const unsigned short* kfb = k + (size_t)bh * 131072 + l * 8;
    const unsigned short* vfb = vt + (size_t)bh * 131072 + l * 8;

    short8 qf[4];
#pragma unroll
    for (int d = 0; d < 4; d++)
        qf[d] = *(const short8*)(qfb + d * 512);

    // opaque zero C operand (loop-invariant; blocks per-iter zero re-materialization)
    float z = 0.f;
    asm volatile("" : "+v"(z));
    f32x16 FZ;
#pragma unroll
    for (int i = 0; i < 16; i++) FZ[i] = z;

    f32x16 OT0, OT1;
#pragma unroll
    for (int i = 0; i < 16; i++) { OT0[i] = 0.f; OT1[i] = 0.f; }
    float lrow = 0.f;

#pragma unroll 4
    for (int kb = kb0; kb < kb0 + 16; kb++) {
        // loads at use (no reg prefetch): K frags, V frags, mask word
        const unsigned short* kp = kfb + kb * 2048;
        const unsigned short* vp = vfb + kb * 2048;
        short8 kf[4], vf[2][2];
#pragma unroll
        for (int d = 0; d < 4; d++) kf[d] = *(const short8*)(kp + d * 512);
#pragma unroll
        for (int kc = 0; kc < 2; kc++) {
            vf[0][kc] = *(const short8*)(vp + kc * 512);
            vf[1][kc] = *(const short8*)(vp + 1024 + kc * 512);
        }
        const unsigned int wd = mw[kb * 2048 + qb * 32 + c];

        // QK^T; C = opaque zero
        __builtin_amdgcn_s_setprio(1);
        f32x16 S = mfma32(kf[0], qf[0], FZ);
#pragma unroll
        for (int d = 1; d < 4; d++) S = mfma32(kf[d], qf[d], S);
        __builtin_amdgcn_s_setprio(0);

        // mask -> -1e9, then p = 2^s via raw v_exp_f32 (exp2(-1e9) = 0 exactly)
        const unsigned int wds = wd >> (4 * hi);
        float p[16];
#pragma unroll
        for (int g = 0; g < 4; g++)
#pragma unroll
            for (int u = 0; u < 4; u++)
                p[g * 4 + u] = (wds & (1u << (8 * g + u))) ? -1e9f : S[g * 4 + u];
#pragma unroll
        for (int i = 0; i < 16; i++) p[i] = fexp2(p[i]);

        // f32 row-sum (R11-proven): in-lane tree + shfl_xor(32)
        float rs = (((p[0] + p[1]) + (p[2] + p[3])) + ((p[4] + p[5]) + (p[6] + p[7]))) +
                   (((p[8] + p[9]) + (p[10] + p[11])) + ((p[12] + p[13]) + (p[14] + p[15])));
        rs += __shfl_xor(rs, 32);
        lrow += rs;

        // P -> bf16 A-frag: 8 cvt_pk + 4 permlane32_swap (T12)
        unsigned w8[8];
#pragma unroll
        for (int g = 0; g < 4; g++) {
            w8[2 * g]     = cvtpk(p[4 * g], p[4 * g + 1]);
            w8[2 * g + 1] = cvtpk(p[4 * g + 2], p[4 * g + 3]);
        }
        short8 pa[2];
#pragma unroll
        for (int kc = 0; kc < 2; kc++) {
            unsigned a0 = w8[4 * kc], a2 = w8[4 * kc + 2];
            plswap(a0, a2);
            unsigned a1 = w8[4 * kc + 1], a3 = w8[4 * kc + 3];
            plswap(a1, a3);
            uint4v tv; tv[0] = a0; tv[1] = a1; tv[2] = a2; tv[3] = a3;
            pa[kc] = __builtin_bit_cast(short8, tv);
        }

        // PV: O^T[d][q] += V^T * P
        __builtin_amdgcn_s_setprio(1);
        OT0 = mfma32(vf[0][0], pa[0], OT0);
        OT0 = mfma32(vf[0][1], pa[1], OT0);
        OT1 = mfma32(vf[1][0], pa[0], OT1);
        OT1 = mfma32(vf[1][1], pa[1], OT1);
        __builtin_amdgcn_s_setprio(0);
    }

    // 2-region add-in combine. region r holds chunks {r, r+2} summed.
    float* R = CL[w & 1];
    if (w < 2) {
#pragma unroll
        for (int i = 0; i < 16; i++) {
            const int kr = (i & 3) + 8 * (i >> 2) + 4 * hi;
            R[kr * 32 + c]        = OT0[i];
            R[(32 + kr) * 32 + c] = OT1[i];
        }
        if (hi == 0) R[2048 + c] = lrow;
    }
    __syncthreads();
    if (w >= 2) {
#pragma unroll
        for (int i = 0; i < 16; i++) {
            const int kr = (i & 3) + 8 * (i >> 2) + 4 * hi;
            R[kr * 32 + c]        += OT0[i];
            R[(32 + kr) * 32 + c] += OT1[i];
        }
        if (hi == 0) R[2048 + c] += lrow;
    }
    __syncthreads();

    // final transpose-store: lane qq = l>>1; wave w covers d-quarter w*16, l&1 picks
    // the 8-col half. O = (region0 + region1) / (l0 + l1), 16B store per lane.
    const int qq = l >> 1, d0 = w * 16 + (l & 1) * 8;
    const float inv = 1.0f / (CL[0][2048 + qq] + CL[1][2048 + qq]);
    const int row = b * 2048 + qb * 32 + qq;
    unsigned short* gout = ao + (size_t)row * 1024 + h * 64 + d0;
    uint4v pk;
#pragma unroll
    for (int u = 0; u < 4; u++) {
        const int d = d0 + 2 * u;
        float a0 = CL[0][d * 32 + qq]       + CL[1][d * 32 + qq];
        float a1 = CL[0][(d + 1) * 32 + qq] + CL[1][(d + 1) * 32 + qq];
        pk[u] = cvtpk(a0 * inv, a1 * inv);
    }
    *(uint4v*)gout = pk;
}

// ---------------- launcher ----------------
extern "C" void kernel_launch(void* const* d_in, const int* in_sizes, int n_in,
                              void* d_out, int out_size, void* d_ws, size_t ws_size,
                              hipStream_t stream) {
    const float* x     = (const float*)d_in[0];
    const int*   mask  = (const int*)d_in[1];
    const float* qkv_w = (const float*)d_in[2];
    const float* qkv_b = (const float*)d_in[3];
    const float* fc_w  = (const float*)d_in[4];
    const float* fc_b  = (const float*)d_in[5];
    float* out = (float*)d_out;

    char* ws = (char*)d_ws;
    size_t off = 0;
    auto alloc = [&](size_t bytes) {
        off = (off + 255) & ~(size_t)255;
        void* p = ws + off;
        off += bytes;
        return p;
    };
    float*          pe     = (float*)alloc(2 * 1024 * 4);
    unsigned int*   mwords = (unsigned int*)alloc((size_t)2048 * 64 * 4);
    unsigned short* xb     = (unsigned short*)alloc((size_t)4096 * 1024 * 2);
    unsigned short* wqkv   = (unsigned short*)alloc((size_t)3072 * 1024 * 2);
    unsigned short* wfc    = (unsigned short*)alloc((size_t)1024 * 1024 * 2);
    unsigned short* qb16   = (unsigned short*)alloc((size_t)2 * 16 * 2048 * 64 * 2);
    unsigned short* kb16   = (unsigned short*)alloc((size_t)2 * 16 * 2048 * 64 * 2);
    unsigned short* vtb    = (unsigned short*)alloc((size_t)2 * 16 * 64 * 2048 * 2);
    unsigned short* attn_o = (unsigned short*)alloc((size_t)4096 * 1024 * 2);

    prep<<<dim3(8705), 256, 0, stream>>>(x, qkv_w, fc_w, mask, xb, wqkv, wfc, mwords, pe);
    qkv_gemm<<<dim3(768), 256, 0, stream>>>(xb, wqkv, qkv_b, pe, qb16, kb16, vtb);
    attn<<<dim3(2048), 256, 0, stream>>>(qb16, kb16, vtb, mwords, attn_o);
    fc_gemm<<<dim3(512), 256, 0, stream>>>(attn_o, wfc, fc_b, out);
}